// Round 4
// baseline (863.188 us; speedup 1.0000x reference)
//
#include <hip/hip_runtime.h>
#include <hip/hip_bf16.h>
#include <stdint.h>

#define TOK 8192
#define DD 1024
#define FF 4096
#define EE 8
#define BM 128
#define BN 128
#define BK 64
#define MT_MAX 72  // max Σ_e ceil(cnt_e/128)

typedef __attribute__((ext_vector_type(8))) short bf16x8;
typedef __attribute__((ext_vector_type(4))) float f32x4;

// ---- workspace layout (bytes) ----
#define WS_SEL    0u
#define WS_CNT    32768u
#define WS_CUR    (32768u + 64u)
#define WS_TSTART (32768u + 128u)
#define WS_ZSUM   (32768u + 192u)
#define WS_PERM   33024u                         // int[9216]
#define WS_XB     131072u                        // bf16[8192*1024]   16 MB
#define WS_H      (WS_XB + 16777216u)            // bf16[9216*4096]   75.5 MB
#define WS_W1B    (WS_H + 75497472u)             // bf16[8*4096*1024] 67 MB
#define WS_W2B    (WS_W1B + 67108864u)           // bf16[8*1024*4096] 67 MB
#define WS_NEED   ((size_t)WS_W2B + 67108864u)   // ~216 MB

__device__ __forceinline__ unsigned short f2bf(float f) {
  unsigned int u = __builtin_bit_cast(unsigned int, f);
  u = (u + 0x7FFFu + ((u >> 16) & 1u)) >> 16;
  return (unsigned short)u;
}

__device__ __forceinline__ void async_copy16(const void* g, void* l) {
  __builtin_amdgcn_global_load_lds(
      (const __attribute__((address_space(1))) unsigned int*)g,
      (__attribute__((address_space(3))) unsigned int*)l, 16, 0, 0);
}

// ---------------- f32 -> bf16 bulk convert ----------------
__global__ __launch_bounds__(256) void k_convert(const float* __restrict__ src,
                                                 unsigned short* __restrict__ dst,
                                                 int n4) {
  for (int i = (int)blockIdx.x * 256 + threadIdx.x; i < n4; i += (int)gridDim.x * 256) {
    const float4 v = ((const float4*)src)[i];
    ushort4 b;
    b.x = f2bf(v.x); b.y = f2bf(v.y); b.z = f2bf(v.z); b.w = f2bf(v.w);
    ((ushort4*)dst)[i] = b;
  }
}

// ---------------- router: logits (f64 acc), argmax, z-loss, x -> bf16 ----------------
__global__ __launch_bounds__(256) void k_router(const float* __restrict__ x,
                                                const float* __restrict__ gw,
                                                uint8_t* __restrict__ ws) {
  const int wv = threadIdx.x >> 6, l = threadIdx.x & 63;
  const int t = (int)blockIdx.x * 4 + wv;
  int* sel = (int*)(ws + WS_SEL);
  int* cnt = (int*)(ws + WS_CNT);
  float* zsum = (float*)(ws + WS_ZSUM);
  unsigned short* xb = (unsigned short*)(ws + WS_XB);
  const float4* xr = (const float4*)(x + (size_t)t * DD);
  double acc[EE];
#pragma unroll
  for (int e = 0; e < EE; ++e) acc[e] = 0.0;
#pragma unroll
  for (int i = 0; i < 4; ++i) {
    const int idx = l + i * 64;
    const float4 v = xr[idx];
    ushort4 b;
    b.x = f2bf(v.x); b.y = f2bf(v.y); b.z = f2bf(v.z); b.w = f2bf(v.w);
    *(ushort4*)(xb + (size_t)t * DD + (size_t)idx * 4) = b;
#pragma unroll
    for (int e = 0; e < EE; ++e) {
      const float4 g = ((const float4*)(gw + (size_t)e * DD))[idx];
      acc[e] += (double)v.x * g.x + (double)v.y * g.y +
                (double)v.z * g.z + (double)v.w * g.w;
    }
  }
#pragma unroll
  for (int e = 0; e < EE; ++e) {
#pragma unroll
    for (int s = 32; s > 0; s >>= 1) acc[e] += __shfl_xor(acc[e], s, 64);
  }
  if (l == 0) {
    double m = acc[0]; int am = 0;
#pragma unroll
    for (int e = 1; e < EE; ++e) if (acc[e] > m) { m = acc[e]; am = e; }
    float se = 0.f;
#pragma unroll
    for (int e = 0; e < EE; ++e) se += __expf((float)(acc[e] - m));
    const float lse = (float)m + __logf(se);
    sel[t] = am;
    atomicAdd(cnt + am, 1);
    atomicAdd(zsum, lse * lse);
  }
}

// ---------------- finalize: segment scan + scalar losses ----------------
__global__ void k_finalize(uint8_t* __restrict__ ws, float* __restrict__ out) {
  if (threadIdx.x != 0 || blockIdx.x != 0) return;
  int* cnt = (int*)(ws + WS_CNT);
  int* cur = (int*)(ws + WS_CUR);
  int* ts = (int*)(ws + WS_TSTART);
  int tiles = 0, s = 0;
  for (int e = 0; e < EE; ++e) {
    ts[e] = tiles;
    cur[e] = tiles * BM;
    tiles += (cnt[e] + BM - 1) / BM;
    s += cnt[e];
  }
  ts[EE] = tiles;
  const float zs = *(float*)(ws + WS_ZSUM);
  out[(size_t)TOK * DD] = (float)EE * ((float)s / (float)TOK);   // aux_loss
  out[(size_t)TOK * DD + 1] = zs / (float)TOK;                   // z_loss
}

// ---------------- scatter: build permutation ----------------
__global__ __launch_bounds__(256) void k_scatter(uint8_t* __restrict__ ws) {
  const int t = (int)blockIdx.x * 256 + threadIdx.x;
  if (t >= TOK) return;
  const int e = ((const int*)(ws + WS_SEL))[t];
  const int pos = atomicAdd((int*)(ws + WS_CUR) + e, 1);
  ((int*)(ws + WS_PERM))[pos] = t;
}

// ---------------- grouped GEMM (C = A * W^T + bias), 128x128 tile ----------------
// BF16B: B staged via global_load_lds from pre-converted bf16 weights.
// KSPLIT: split-K with f32 atomicAdd combine (GEMM2 TLP).
template <int K, int NTOT, int KSPLIT, bool DOGELU, bool INDIRECT, bool BF16B>
__global__ __launch_bounds__(256) void k_gemm(const unsigned short* __restrict__ A,
                                              const float* __restrict__ Wf,
                                              const unsigned short* __restrict__ Wb,
                                              const float* __restrict__ bias,
                                              uint8_t* __restrict__ ws,
                                              float* __restrict__ out) {
  const int* ts = (const int*)(ws + WS_TSTART);
  const int* perm = (const int*)(ws + WS_PERM);
  unsigned short* H = (unsigned short*)(ws + WS_H);

  // bijective XCD-chunked swizzle; wg order: mt fast, then nt, then kh
  const int MT = (int)gridDim.x;
  const int NT = NTOT / BN;
  const int nblk = MT * (int)gridDim.y;
  const int orig = (int)blockIdx.y * MT + (int)blockIdx.x;
  const int q = nblk >> 3, r = nblk & 7;
  const int xcd = orig & 7, b8 = orig >> 3;
  const int wg = (xcd < r ? xcd * (q + 1) : r * (q + 1) + (xcd - r) * q) + b8;
  const int mt = wg % MT;
  const int rest = wg / MT;
  const int nt = rest % NT;
  const int kh = rest / NT;

  if (mt >= ts[EE]) return;
  int e = 0;
#pragma unroll
  for (int i = 1; i < EE; ++i) if (mt >= ts[i]) e = i;

  const int m0 = mt * BM, n0 = nt * BN;
  const float* bs = bias + (size_t)e * NTOT;

  __shared__ __align__(16) unsigned short As[BM * BK];
  __shared__ __align__(16) unsigned short Bs[BN * BK];

  const int tid = threadIdx.x, wv = tid >> 6, l = tid & 63;
  const int wr = wv >> 1, wc = wv & 1;

  f32x4 acc[4][4];
#pragma unroll
  for (int m = 0; m < 4; ++m)
#pragma unroll
    for (int n = 0; n < 4; ++n) acc[m][n] = f32x4{0.f, 0.f, 0.f, 0.f};

  int arow[4];
#pragma unroll
  for (int j = 0; j < 4; ++j) {
    const int row = (tid + j * 256) >> 3;
    if (INDIRECT) {
      const int tk = perm[m0 + row];
      arow[j] = tk < 0 ? 0 : tk;
    } else {
      arow[j] = m0 + row;
    }
  }

  const int kbeg = kh * (K / KSPLIT), kend = kbeg + K / KSPLIT;
  for (int k0 = kbeg; k0 < kend; k0 += BK) {
    // A: global_load_lds w16, pre-swizzled source (rule #21)
#pragma unroll
    for (int j = 0; j < 4; ++j) {
      const int p = tid + j * 256;
      const int row = p >> 3, pc = p & 7;
      const int lc = pc ^ (row & 7);
      async_copy16(A + (size_t)arow[j] * K + k0 + lc * 8,
                   (char*)As + (size_t)(j * 256 + wv * 64) * 16);
    }
    if (BF16B) {
      // B: same gload_lds pattern from bf16 weights
#pragma unroll
      for (int j = 0; j < 4; ++j) {
        const int p = tid + j * 256;
        const int row = p >> 3, pc = p & 7;
        const int lc = pc ^ (row & 7);
        async_copy16(Wb + (size_t)e * NTOT * K + (size_t)(n0 + row) * K + k0 + lc * 8,
                     (char*)Bs + (size_t)(j * 256 + wv * 64) * 16);
      }
    } else {
      // B: f32 -> bf16 reg-staged, swizzled ds_write (fallback path)
#pragma unroll
      for (int i = 0; i < 8; ++i) {
        const int c = tid + i * 256;
        const int row = c >> 4, cc = c & 15;
        const float4 v = *(const float4*)(Wf + (size_t)e * NTOT * K +
                                          (size_t)(n0 + row) * K + k0 + cc * 4);
        uint2 u;
        u.x = (unsigned)f2bf(v.x) | ((unsigned)f2bf(v.y) << 16);
        u.y = (unsigned)f2bf(v.z) | ((unsigned)f2bf(v.w) << 16);
        const int phys = row * 128 + (((cc >> 1) ^ (row & 7)) << 4) + ((cc & 1) << 3);
        *(uint2*)((char*)Bs + phys) = u;
      }
    }
    __syncthreads();
#pragma unroll
    for (int kk = 0; kk < 2; ++kk) {
      const int ch = kk * 4 + (l >> 4);
      bf16x8 af[4], bfr[4];
#pragma unroll
      for (int m = 0; m < 4; ++m) {
        const int row = wr * 64 + m * 16 + (l & 15);
        af[m] = *(const bf16x8*)((const char*)As + row * 128 + ((ch ^ (row & 7)) << 4));
      }
#pragma unroll
      for (int n = 0; n < 4; ++n) {
        const int row = wc * 64 + n * 16 + (l & 15);
        bfr[n] = *(const bf16x8*)((const char*)Bs + row * 128 + ((ch ^ (row & 7)) << 4));
      }
#pragma unroll
      for (int m = 0; m < 4; ++m)
#pragma unroll
        for (int n = 0; n < 4; ++n)
          acc[m][n] = __builtin_amdgcn_mfma_f32_16x16x32_bf16(af[m], bfr[n], acc[m][n], 0, 0, 0);
    }
    __syncthreads();
  }

  // epilogue: C layout col = lane&15, row = (lane>>4)*4 + reg [m89]
  const int cl = l & 15, rg = l >> 4;
#pragma unroll
  for (int n = 0; n < 4; ++n) {
    const int col = n0 + wc * 64 + n * 16 + cl;
    const float bv = (KSPLIT == 1 || kh == 0) ? bs[col] : 0.f;
#pragma unroll
    for (int m = 0; m < 4; ++m) {
      const int rbase = m0 + wr * 64 + m * 16 + rg * 4;
#pragma unroll
      for (int qq = 0; qq < 4; ++qq) {
        const int rr = rbase + qq;
        float v = acc[m][n][qq] + bv;
        if (DOGELU) {
          const float u0 = 0.7978845608028654f * (v + 0.044715f * v * v * v);
          const float th = 1.f - 2.f / (__expf(2.f * u0) + 1.f);  // tanh
          v = 0.5f * v * (1.f + th);
          H[(size_t)rr * FF + col] = f2bf(v);
        } else {
          const int tk = perm[rr];
          if (tk >= 0) {
            if (KSPLIT == 1) out[(size_t)tk * DD + col] = v;
            else atomicAdd(out + (size_t)tk * DD + col, v);
          }
        }
      }
    }
  }
}

extern "C" void kernel_launch(void* const* d_in, const int* in_sizes, int n_in,
                              void* d_out, int out_size, void* d_ws, size_t ws_size,
                              hipStream_t stream) {
  const float* x = (const float*)d_in[0];
  const float* gw = (const float*)d_in[1];
  const float* w1 = (const float*)d_in[2];
  const float* b1 = (const float*)d_in[3];
  const float* w2 = (const float*)d_in[4];
  const float* b2 = (const float*)d_in[5];
  float* out = (float*)d_out;
  uint8_t* ws = (uint8_t*)d_ws;
  const bool full = ws_size >= WS_NEED;  // constant across calls -> graph-safe

  hipMemsetAsync(ws + WS_CNT, 0, 256, stream);
  hipMemsetAsync(ws + WS_PERM, 0xFF, MT_MAX * BM * 4, stream);
  hipMemsetAsync(out, 0, (size_t)TOK * DD * 4, stream);  // split-K accumulates

  unsigned short* w1b = (unsigned short*)(ws + WS_W1B);
  unsigned short* w2b = (unsigned short*)(ws + WS_W2B);
  if (full) {
    k_convert<<<2048, 256, 0, stream>>>(w1, w1b, EE * FF * DD / 4);
    k_convert<<<2048, 256, 0, stream>>>(w2, w2b, EE * DD * FF / 4);
  }

  k_router<<<TOK / 4, 256, 0, stream>>>(x, gw, ws);
  k_finalize<<<1, 64, 0, stream>>>(ws, out);
  k_scatter<<<TOK / 256, 256, 0, stream>>>(ws);

  const unsigned short* Xb = (const unsigned short*)(ws + WS_XB);
  const unsigned short* Hb = (const unsigned short*)(ws + WS_H);
  if (full) {
    k_gemm<DD, FF, 1, true, true, true>
        <<<dim3(MT_MAX, FF / BN), 256, 0, stream>>>(Xb, w1, w1b, b1, ws, out);
    k_gemm<FF, DD, 2, false, false, true>
        <<<dim3(MT_MAX, (DD / BN) * 2), 256, 0, stream>>>(Hb, w2, w2b, b2, ws, out);
  } else {
    k_gemm<DD, FF, 1, true, true, false>
        <<<dim3(MT_MAX, FF / BN), 256, 0, stream>>>(Xb, w1, w1b, b1, ws, out);
    k_gemm<FF, DD, 2, false, false, false>
        <<<dim3(MT_MAX, (DD / BN) * 2), 256, 0, stream>>>(Hb, w2, w2b, b2, ws, out);
  }
}

// Round 10
// 824.453 us; speedup vs baseline: 1.0470x; 1.0470x over previous
//
#include <hip/hip_runtime.h>
#include <hip/hip_bf16.h>
#include <stdint.h>

#define TOK 8192
#define DD 1024
#define FF 4096
#define EE 8
#define BM 256
#define BN 256
#define BK 64
#define NW 512
#define MT_MAX 40  // max Σ_e ceil(cnt_e/256) = 32 + 7 pads

typedef __attribute__((ext_vector_type(8))) short bf16x8;
typedef __attribute__((ext_vector_type(4))) float f32x4;

// ---- workspace layout (bytes); total ~160.1 MB (proven budget >=216 MB) ----
#define WS_SEL    0u
#define WS_CNT    32768u
#define WS_CUR    32832u
#define WS_TSTART 32896u
#define WS_ZSUM   32960u
#define WS_PERM   33024u                      // int[10240] = 40*256
#define WS_XB     131072u                     // bf16[8192*1024]   16 MB
#define WS_H      (WS_XB + 16777216u)         // bf16[10240*4096]  80 MB
#define WS_WB     (WS_H + 83886080u)          // bf16[8*4096*1024] 64 MB (w1b, then w2b)

__device__ __forceinline__ unsigned short f2bf(float f) {
  unsigned int u = __builtin_bit_cast(unsigned int, f);
  u = (u + 0x7FFFu + ((u >> 16) & 1u)) >> 16;
  return (unsigned short)u;
}

__device__ __forceinline__ void async_copy16(const void* g, void* l) {
  __builtin_amdgcn_global_load_lds(
      (const __attribute__((address_space(1))) unsigned int*)g,
      (__attribute__((address_space(3))) unsigned int*)l, 16, 0, 0);
}

// ---------------- f32 -> bf16 bulk convert ----------------
__global__ __launch_bounds__(256) void k_convert(const float* __restrict__ src,
                                                 unsigned short* __restrict__ dst,
                                                 int n4) {
  for (int i = (int)blockIdx.x * 256 + threadIdx.x; i < n4; i += (int)gridDim.x * 256) {
    const float4 v = ((const float4*)src)[i];
    ushort4 b;
    b.x = f2bf(v.x); b.y = f2bf(v.y); b.z = f2bf(v.z); b.w = f2bf(v.w);
    ((ushort4*)dst)[i] = b;
  }
}

// ---------------- router: logits (f64 acc), argmax, z-loss, x -> bf16 ----------------
__global__ __launch_bounds__(256) void k_router(const float* __restrict__ x,
                                                const float* __restrict__ gw,
                                                uint8_t* __restrict__ ws) {
  const int wv = threadIdx.x >> 6, l = threadIdx.x & 63;
  const int t = (int)blockIdx.x * 4 + wv;
  int* sel = (int*)(ws + WS_SEL);
  int* cnt = (int*)(ws + WS_CNT);
  float* zsum = (float*)(ws + WS_ZSUM);
  unsigned short* xb = (unsigned short*)(ws + WS_XB);
  const float4* xr = (const float4*)(x + (size_t)t * DD);
  double acc[EE];
#pragma unroll
  for (int e = 0; e < EE; ++e) acc[e] = 0.0;
#pragma unroll
  for (int i = 0; i < 4; ++i) {
    const int idx = l + i * 64;
    const float4 v = xr[idx];
    ushort4 b;
    b.x = f2bf(v.x); b.y = f2bf(v.y); b.z = f2bf(v.z); b.w = f2bf(v.w);
    *(ushort4*)(xb + (size_t)t * DD + (size_t)idx * 4) = b;
#pragma unroll
    for (int e = 0; e < EE; ++e) {
      const float4 g = ((const float4*)(gw + (size_t)e * DD))[idx];
      acc[e] += (double)v.x * g.x + (double)v.y * g.y +
                (double)v.z * g.z + (double)v.w * g.w;
    }
  }
#pragma unroll
  for (int e = 0; e < EE; ++e) {
#pragma unroll
    for (int s = 32; s > 0; s >>= 1) acc[e] += __shfl_xor(acc[e], s, 64);
  }
  if (l == 0) {
    double m = acc[0]; int am = 0;
#pragma unroll
    for (int e = 1; e < EE; ++e) if (acc[e] > m) { m = acc[e]; am = e; }
    float se = 0.f;
#pragma unroll
    for (int e = 0; e < EE; ++e) se += __expf((float)(acc[e] - m));
    const float lse = (float)m + __logf(se);
    sel[t] = am;
    atomicAdd(cnt + am, 1);
    atomicAdd(zsum, lse * lse);
  }
}

// ---------------- finalize: 256-aligned segment scan + scalar losses ----------------
__global__ void k_finalize(uint8_t* __restrict__ ws, float* __restrict__ out) {
  if (threadIdx.x != 0 || blockIdx.x != 0) return;
  int* cnt = (int*)(ws + WS_CNT);
  int* cur = (int*)(ws + WS_CUR);
  int* ts = (int*)(ws + WS_TSTART);
  int tiles = 0, s = 0;
  for (int e = 0; e < EE; ++e) {
    ts[e] = tiles;
    cur[e] = tiles * BM;
    tiles += (cnt[e] + BM - 1) / BM;
    s += cnt[e];
  }
  ts[EE] = tiles;
  const float zs = *(float*)(ws + WS_ZSUM);
  out[(size_t)TOK * DD] = (float)EE * ((float)s / (float)TOK);   // aux_loss
  out[(size_t)TOK * DD + 1] = zs / (float)TOK;                   // z_loss
}

// ---------------- scatter: build permutation ----------------
__global__ __launch_bounds__(256) void k_scatter(uint8_t* __restrict__ ws) {
  const int t = (int)blockIdx.x * 256 + threadIdx.x;
  if (t >= TOK) return;
  const int e = ((const int*)(ws + WS_SEL))[t];
  const int pos = atomicAdd((int*)(ws + WS_CUR) + e, 1);
  ((int*)(ws + WS_PERM))[pos] = t;
}

// ---------------- grouped GEMM, 256x256 tile, 2-phase double-buffered ----------------
// 512 threads = 8 waves (2M x 4N), per-wave 128x64 output, BK=64, LDS 128 KB.
// Stage tile t+1 BEFORE computing tile t; one vmcnt(0)+barrier per K-step (T3-min).
template <int K, int NTOT, int KSPLIT, bool DOGELU, bool INDIRECT>
__global__ __launch_bounds__(NW, 2) void k_gemm256(const unsigned short* __restrict__ A,
                                                   const unsigned short* __restrict__ W,
                                                   const float* __restrict__ bias,
                                                   uint8_t* __restrict__ ws,
                                                   float* __restrict__ out) {
  const int* ts = (const int*)(ws + WS_TSTART);
  const int* perm = (const int*)(ws + WS_PERM);
  unsigned short* H = (unsigned short*)(ws + WS_H);

  // bijective XCD-chunked swizzle; orig order: mt fast, then nt, then kh
  const int MT = (int)gridDim.x;
  const int NT = NTOT / BN;
  const int nblk = MT * (int)gridDim.y;
  const int orig = (int)blockIdx.y * MT + (int)blockIdx.x;
  const int q = nblk >> 3, r = nblk & 7;
  const int xcd = orig & 7, b8 = orig >> 3;
  const int wg = (xcd < r ? xcd * (q + 1) : r * (q + 1) + (xcd - r) * q) + b8;
  const int mt = wg % MT;
  const int rest = wg / MT;
  const int nt = rest % NT;
  const int kh = rest / NT;

  if (mt >= ts[EE]) return;
  int e = 0;
#pragma unroll
  for (int i = 1; i < EE; ++i) if (mt >= ts[i]) e = i;

  const int m0 = mt * BM, n0 = nt * BN;
  const unsigned short* We = W + (size_t)e * NTOT * K;
  const float* bs = bias + (size_t)e * NTOT;

  __shared__ __align__(16) unsigned short sm[2][2][BM * BK];  // [buf][A/B], 128 KB

  const int tid = threadIdx.x, wid = tid >> 6, l = tid & 63;
  const int wr = wid >> 2, wc = wid & 3;

  f32x4 acc[8][4];
#pragma unroll
  for (int m = 0; m < 8; ++m)
#pragma unroll
    for (int n = 0; n < 4; ++n) acc[m][n] = f32x4{0.f, 0.f, 0.f, 0.f};

  int arow[4], brow[4];
#pragma unroll
  for (int j = 0; j < 4; ++j) {
    const int row = (tid + j * NW) >> 3;
    if (INDIRECT) {
      const int tk = perm[m0 + row];
      arow[j] = tk < 0 ? 0 : tk;  // pads: token 0 (finite garbage, masked at store)
    } else {
      arow[j] = m0 + row;
    }
    brow[j] = n0 + row;
  }

  const int kbeg = kh * (K / KSPLIT);
  const int NS = (K / KSPLIT) / BK;

  // rule #21: linear LDS dest + inverse-swizzled global src + swizzled read
  auto stage = [&](int buf, int k0) {
#pragma unroll
    for (int j = 0; j < 4; ++j) {
      const int p = tid + j * NW;
      const int row = p >> 3, pc = p & 7;
      const int lc = pc ^ (row & 7);
      async_copy16(A + (size_t)arow[j] * K + k0 + lc * 8,
                   (char*)&sm[buf][0][0] + (size_t)p * 16);
      async_copy16(We + (size_t)brow[j] * K + k0 + lc * 8,
                   (char*)&sm[buf][1][0] + (size_t)p * 16);
    }
  };

  stage(0, kbeg);
  asm volatile("s_waitcnt vmcnt(0)" ::: "memory");
  __syncthreads();

  int cur = 0;
  for (int t = 0; t < NS; ++t) {
    if (t + 1 < NS) stage(cur ^ 1, kbeg + (t + 1) * BK);  // prefetch: overlap HBM w/ MFMA
    const char* Ab = (const char*)&sm[cur][0][0];
    const char* Bb = (const char*)&sm[cur][1][0];
#pragma unroll
    for (int kk = 0; kk < 2; ++kk) {
      const int ch = kk * 4 + (l >> 4);
      bf16x8 af[8], bf_[4];
#pragma unroll
      for (int m = 0; m < 8; ++m) {
        const int row = wr * 128 + m * 16 + (l & 15);
        af[m] = *(const bf16x8*)(Ab + row * 128 + ((ch ^ (row & 7)) << 4));
      }
#pragma unroll
      for (int n = 0; n < 4; ++n) {
        const int row = wc * 64 + n * 16 + (l & 15);
        bf_[n] = *(const bf16x8*)(Bb + row * 128 + ((ch ^ (row & 7)) << 4));
      }
#pragma unroll
      for (int m = 0; m < 8; ++m)
#pragma unroll
        for (int n = 0; n < 4; ++n)
          acc[m][n] = __builtin_amdgcn_mfma_f32_16x16x32_bf16(af[m], bf_[n], acc[m][n], 0, 0, 0);
    }
    asm volatile("s_waitcnt vmcnt(0)" ::: "memory");  // next tile staged
    __syncthreads();                                  // all reads of sm[cur] done
    cur ^= 1;
  }

  // epilogue: C layout col = lane&15, row = (lane>>4)*4 + reg [m89]
  const int cl = l & 15, rg = l >> 4;
#pragma unroll
  for (int n = 0; n < 4; ++n) {
    const int col = n0 + wc * 64 + n * 16 + cl;
    const float bv = (KSPLIT == 1 || kh == 0) ? bs[col] : 0.f;
#pragma unroll
    for (int m = 0; m < 8; ++m) {
      const int rbase = m0 + wr * 128 + m * 16 + rg * 4;
#pragma unroll
      for (int qq = 0; qq < 4; ++qq) {
        const int rr = rbase + qq;
        float v = acc[m][n][qq] + bv;
        if (DOGELU) {
          const float u0 = 0.7978845608028654f * (v + 0.044715f * v * v * v);
          const float th = 1.f - 2.f / (__expf(2.f * u0) + 1.f);  // tanh
          v = 0.5f * v * (1.f + th);
          H[(size_t)rr * FF + col] = f2bf(v);
        } else {
          const int tk = perm[rr];
          if (tk >= 0) {
            if (KSPLIT == 1) out[(size_t)tk * DD + col] = v;
            else atomicAdd(out + (size_t)tk * DD + col, v);
          }
        }
      }
    }
  }
}

extern "C" void kernel_launch(void* const* d_in, const int* in_sizes, int n_in,
                              void* d_out, int out_size, void* d_ws, size_t ws_size,
                              hipStream_t stream) {
  const float* x = (const float*)d_in[0];
  const float* gw = (const float*)d_in[1];
  const float* w1 = (const float*)d_in[2];
  const float* b1 = (const float*)d_in[3];
  const float* w2 = (const float*)d_in[4];
  const float* b2 = (const float*)d_in[5];
  float* out = (float*)d_out;
  uint8_t* ws = (uint8_t*)d_ws;

  hipMemsetAsync(ws + WS_CNT, 0, 256, stream);
  hipMemsetAsync(ws + WS_PERM, 0xFF, MT_MAX * BM * 4, stream);
  hipMemsetAsync(out, 0, (size_t)TOK * DD * 4, stream);  // split-K accumulates

  unsigned short* wb = (unsigned short*)(ws + WS_WB);
  const unsigned short* Xb = (const unsigned short*)(ws + WS_XB);
  const unsigned short* Hb = (const unsigned short*)(ws + WS_H);

  k_convert<<<2048, 256, 0, stream>>>(w1, wb, EE * FF * DD / 4);
  k_router<<<TOK / 4, 256, 0, stream>>>(x, gw, ws);
  k_finalize<<<1, 64, 0, stream>>>(ws, out);
  k_scatter<<<TOK / 256, 256, 0, stream>>>(ws);

  // GEMM1: [tokens x DD] @ w1^T -> gelu -> H   (grid 40 x 16)
  k_gemm256<DD, FF, 1, true, true>
      <<<dim3(MT_MAX, FF / BN), NW, 0, stream>>>(Xb, wb, b1, ws, out);

  // convert w2 into the SAME buffer (w1b dead after GEMM1; stream-serial)
  k_convert<<<2048, 256, 0, stream>>>(w2, wb, EE * DD * FF / 4);

  // GEMM2: H @ w2^T -> scatter to out, split-K x4 (grid 40 x 16)
  k_gemm256<FF, DD, 4, false, false>
      <<<dim3(MT_MAX, (DD / BN) * 4), NW, 0, stream>>>(Hb, wb, b2, ws, out);
}

// Round 13
// 801.478 us; speedup vs baseline: 1.0770x; 1.0287x over previous
//
#include <hip/hip_runtime.h>
#include <hip/hip_bf16.h>
#include <stdint.h>

#define TOK 8192
#define DD 1024
#define FF 4096
#define EE 8
#define BM 256
#define BN 256
#define BK 32
#define NW 512
#define MT_MAX 40  // max Σ_e ceil(cnt_e/256) = 32 + 7 pads

typedef __attribute__((ext_vector_type(8))) short bf16x8;
typedef __attribute__((ext_vector_type(4))) float f32x4;

// ---- workspace layout (bytes); total ~160.1 MB ----
#define WS_SEL    0u
#define WS_CNT    32768u
#define WS_CUR    32832u
#define WS_TSTART 32896u
#define WS_ZSUM   32960u
#define WS_PERM   33024u                      // int[10240] = 40*256
#define WS_XB     131072u                     // bf16[8192*1024]   16 MB
#define WS_H      (WS_XB + 16777216u)         // bf16[10240*4096]  80 MB
#define WS_WB     (WS_H + 83886080u)          // bf16[8*4096*1024] 64 MB (w1b, then w2b)

__device__ __forceinline__ unsigned short f2bf(float f) {
  unsigned int u = __builtin_bit_cast(unsigned int, f);
  u = (u + 0x7FFFu + ((u >> 16) & 1u)) >> 16;
  return (unsigned short)u;
}

__device__ __forceinline__ void async_copy16(const void* g, void* l) {
  __builtin_amdgcn_global_load_lds(
      (const __attribute__((address_space(1))) unsigned int*)g,
      (__attribute__((address_space(3))) unsigned int*)l, 16, 0, 0);
}

// ---------------- f32 -> bf16 bulk convert ----------------
__global__ __launch_bounds__(256) void k_convert(const float* __restrict__ src,
                                                 unsigned short* __restrict__ dst,
                                                 int n4) {
  for (int i = (int)blockIdx.x * 256 + threadIdx.x; i < n4; i += (int)gridDim.x * 256) {
    const float4 v = ((const float4*)src)[i];
    ushort4 b;
    b.x = f2bf(v.x); b.y = f2bf(v.y); b.z = f2bf(v.z); b.w = f2bf(v.w);
    ((ushort4*)dst)[i] = b;
  }
}

// ---------------- router: logits (f64 acc), argmax, z-loss, x -> bf16 ----------------
__global__ __launch_bounds__(256) void k_router(const float* __restrict__ x,
                                                const float* __restrict__ gw,
                                                uint8_t* __restrict__ ws) {
  const int wv = threadIdx.x >> 6, l = threadIdx.x & 63;
  const int t = (int)blockIdx.x * 4 + wv;
  int* sel = (int*)(ws + WS_SEL);
  int* cnt = (int*)(ws + WS_CNT);
  float* zsum = (float*)(ws + WS_ZSUM);
  unsigned short* xb = (unsigned short*)(ws + WS_XB);
  const float4* xr = (const float4*)(x + (size_t)t * DD);
  double acc[EE];
#pragma unroll
  for (int e = 0; e < EE; ++e) acc[e] = 0.0;
#pragma unroll
  for (int i = 0; i < 4; ++i) {
    const int idx = l + i * 64;
    const float4 v = xr[idx];
    ushort4 b;
    b.x = f2bf(v.x); b.y = f2bf(v.y); b.z = f2bf(v.z); b.w = f2bf(v.w);
    *(ushort4*)(xb + (size_t)t * DD + (size_t)idx * 4) = b;
#pragma unroll
    for (int e = 0; e < EE; ++e) {
      const float4 g = ((const float4*)(gw + (size_t)e * DD))[idx];
      acc[e] += (double)v.x * g.x + (double)v.y * g.y +
                (double)v.z * g.z + (double)v.w * g.w;
    }
  }
#pragma unroll
  for (int e = 0; e < EE; ++e) {
#pragma unroll
    for (int s = 32; s > 0; s >>= 1) acc[e] += __shfl_xor(acc[e], s, 64);
  }
  if (l == 0) {
    double m = acc[0]; int am = 0;
#pragma unroll
    for (int e = 1; e < EE; ++e) if (acc[e] > m) { m = acc[e]; am = e; }
    float se = 0.f;
#pragma unroll
    for (int e = 0; e < EE; ++e) se += __expf((float)(acc[e] - m));
    const float lse = (float)m + __logf(se);
    sel[t] = am;
    atomicAdd(cnt + am, 1);
    atomicAdd(zsum, lse * lse);
  }
}

// ---------------- finalize: 256-aligned segment scan + scalar losses ----------------
__global__ void k_finalize(uint8_t* __restrict__ ws, float* __restrict__ out) {
  if (threadIdx.x != 0 || blockIdx.x != 0) return;
  int* cnt = (int*)(ws + WS_CNT);
  int* cur = (int*)(ws + WS_CUR);
  int* ts = (int*)(ws + WS_TSTART);
  int tiles = 0, s = 0;
  for (int e = 0; e < EE; ++e) {
    ts[e] = tiles;
    cur[e] = tiles * BM;
    tiles += (cnt[e] + BM - 1) / BM;
    s += cnt[e];
  }
  ts[EE] = tiles;
  const float zs = *(float*)(ws + WS_ZSUM);
  out[(size_t)TOK * DD] = (float)EE * ((float)s / (float)TOK);   // aux_loss
  out[(size_t)TOK * DD + 1] = zs / (float)TOK;                   // z_loss
}

// ---------------- scatter: build permutation ----------------
__global__ __launch_bounds__(256) void k_scatter(uint8_t* __restrict__ ws) {
  const int t = (int)blockIdx.x * 256 + threadIdx.x;
  if (t >= TOK) return;
  const int e = ((const int*)(ws + WS_SEL))[t];
  const int pos = atomicAdd((int*)(ws + WS_CUR) + e, 1);
  ((int*)(ws + WS_PERM))[pos] = t;
}

// ---------------- grouped GEMM, 256x256 tile, ring-4 counted-vmcnt pipeline ----------------
// BK=32, ring of 4 LDS buffers (32 KB each). Steady state: 12 loads/wave in flight.
// Step t: ds_read tile t; stage t+3; MFMA; vmcnt(8) [own tile-t+1 loads landed,
// 8 newer stay flying]; s_barrier [all waves confirmed]. Reads happen only AFTER
// a (vmcnt, barrier) pair for that tile -> cross-wave safe (vmcnt is per-wave!).
// T4: never drain to zero mid-loop. LDS row = 64 B; swizzle ch^(r&3)^((r>>2)&3).
template <int K, int NTOT, int KSPLIT, bool DOGELU, bool INDIRECT>
__global__ __launch_bounds__(NW, 2) void k_gemm256(const unsigned short* __restrict__ A,
                                                   const unsigned short* __restrict__ W,
                                                   const float* __restrict__ bias,
                                                   uint8_t* __restrict__ ws,
                                                   float* __restrict__ out) {
  const int* ts = (const int*)(ws + WS_TSTART);
  const int* perm = (const int*)(ws + WS_PERM);
  unsigned short* H = (unsigned short*)(ws + WS_H);

  // bijective XCD-chunked swizzle; orig order: mt fast, then nt, then kh
  const int MT = (int)gridDim.x;
  const int NT = NTOT / BN;
  const int nblk = MT * (int)gridDim.y;
  const int orig = (int)blockIdx.y * MT + (int)blockIdx.x;
  const int q = nblk >> 3, r = nblk & 7;
  const int xcd = orig & 7, b8 = orig >> 3;
  const int wg = (xcd < r ? xcd * (q + 1) : r * (q + 1) + (xcd - r) * q) + b8;
  const int mt = wg % MT;
  const int rest = wg / MT;
  const int nt = rest % NT;
  const int kh = rest / NT;

  if (mt >= ts[EE]) return;
  int e = 0;
#pragma unroll
  for (int i = 1; i < EE; ++i) if (mt >= ts[i]) e = i;

  const int m0 = mt * BM, n0 = nt * BN;
  const unsigned short* We = W + (size_t)e * NTOT * K;
  const float* bs = bias + (size_t)e * NTOT;

  // [buf 0..3][A,B][256 rows x 32 k] = 128 KB
  __shared__ __align__(16) unsigned short sm[4][2][BM * BK];

  const int tid = threadIdx.x, wid = tid >> 6, l = tid & 63;
  const int wr = wid >> 2, wc = wid & 3;

  f32x4 acc[8][4];
#pragma unroll
  for (int m = 0; m < 8; ++m)
#pragma unroll
    for (int n = 0; n < 4; ++n) acc[m][n] = f32x4{0.f, 0.f, 0.f, 0.f};

  int arow[2], brow[2];
#pragma unroll
  for (int j = 0; j < 2; ++j) {
    const int row = (tid + j * NW) >> 2;   // 1024 slots -> 256 rows, 4 slots/row
    if (INDIRECT) {
      const int tk = perm[m0 + row];
      arow[j] = tk < 0 ? 0 : tk;  // pads: token 0 (finite garbage, masked at store)
    } else {
      arow[j] = m0 + row;
    }
    brow[j] = n0 + row;
  }

  const int kbeg = kh * (K / KSPLIT);
  const int NS = (K / KSPLIT) / BK;

  // rule #21: linear LDS dest + inverse-swizzled global src + swizzled read.
  // slot p: row=p>>2, pc=p&3 -> LDS[row][chunk pc] gets global chunk pc^swz(row).
  auto stage = [&](int buf, int k0) {
#pragma unroll
    for (int j = 0; j < 2; ++j) {
      const int p = tid + j * NW;
      const int row = p >> 2, pc = p & 3;
      const int lc = pc ^ (row & 3) ^ ((row >> 2) & 3);
      async_copy16(A + (size_t)arow[j] * K + k0 + lc * 8,
                   (char*)&sm[buf][0][0] + (size_t)p * 16);
      async_copy16(We + (size_t)brow[j] * K + k0 + lc * 8,
                   (char*)&sm[buf][1][0] + (size_t)p * 16);
    }
  };

  // prologue: 3 tiles (12 loads/wave) in flight; own tile-0 landed; collective barrier
  stage(0, kbeg);
  stage(1, kbeg + BK);
  stage(2, kbeg + 2 * BK);
  asm volatile("s_waitcnt vmcnt(8)" ::: "memory");
  __builtin_amdgcn_s_barrier();
  __builtin_amdgcn_sched_barrier(0);

  const int ch = l >> 4;  // 16B chunk of this lane's k-slice
  for (int t = 0; t < NS; ++t) {
    const char* Ab = (const char*)&sm[t & 3][0][0];
    const char* Bb = (const char*)&sm[t & 3][1][0];
    bf16x8 af[8], bf_[4];
#pragma unroll
    for (int m = 0; m < 8; ++m) {
      const int row = wr * 128 + m * 16 + (l & 15);
      const int s = ch ^ (row & 3) ^ ((row >> 2) & 3);
      af[m] = *(const bf16x8*)(Ab + row * 64 + s * 16);
    }
#pragma unroll
    for (int n = 0; n < 4; ++n) {
      const int row = wc * 64 + n * 16 + (l & 15);
      const int s = ch ^ (row & 3) ^ ((row >> 2) & 3);
      bf_[n] = *(const bf16x8*)(Bb + row * 64 + s * 16);
    }
    if (t + 3 < NS) stage((t + 3) & 3, kbeg + (t + 3) * BK);  // refill ring
#pragma unroll
    for (int m = 0; m < 8; ++m)
#pragma unroll
      for (int n = 0; n < 4; ++n)
        acc[m][n] = __builtin_amdgcn_mfma_f32_16x16x32_bf16(af[m], bf_[n], acc[m][n], 0, 0, 0);
    if (t + 1 < NS) {
      // own tile-(t+1) loads landed (counted, never 0 mid-loop), then collective barrier
      if (t + 3 < NS)       asm volatile("s_waitcnt vmcnt(8)" ::: "memory");
      else if (t + 3 == NS) asm volatile("s_waitcnt vmcnt(4)" ::: "memory");
      else                  asm volatile("s_waitcnt vmcnt(0)" ::: "memory");
      __builtin_amdgcn_s_barrier();
      __builtin_amdgcn_sched_barrier(0);
    }
  }

  // epilogue: C layout col = lane&15, row = (lane>>4)*4 + reg [m89]
  const int cl = l & 15, rg = l >> 4;
#pragma unroll
  for (int n = 0; n < 4; ++n) {
    const int col = n0 + wc * 64 + n * 16 + cl;
    const float bv = (KSPLIT == 1 || kh == 0) ? bs[col] : 0.f;
#pragma unroll
    for (int m = 0; m < 8; ++m) {
      const int rbase = m0 + wr * 128 + m * 16 + rg * 4;
#pragma unroll
      for (int qq = 0; qq < 4; ++qq) {
        const int rr = rbase + qq;
        float v = acc[m][n][qq] + bv;
        if (DOGELU) {
          const float u0 = 0.7978845608028654f * (v + 0.044715f * v * v * v);
          const float th = 1.f - 2.f / (__expf(2.f * u0) + 1.f);  // tanh
          v = 0.5f * v * (1.f + th);
          H[(size_t)rr * FF + col] = f2bf(v);
        } else {
          const int tk = perm[rr];
          if (tk >= 0) {
            if (KSPLIT == 1) out[(size_t)tk * DD + col] = v;
            else atomicAdd(out + (size_t)tk * DD + col, v);
          }
        }
      }
    }
  }
}

extern "C" void kernel_launch(void* const* d_in, const int* in_sizes, int n_in,
                              void* d_out, int out_size, void* d_ws, size_t ws_size,
                              hipStream_t stream) {
  const float* x = (const float*)d_in[0];
  const float* gw = (const float*)d_in[1];
  const float* w1 = (const float*)d_in[2];
  const float* b1 = (const float*)d_in[3];
  const float* w2 = (const float*)d_in[4];
  const float* b2 = (const float*)d_in[5];
  float* out = (float*)d_out;
  uint8_t* ws = (uint8_t*)d_ws;

  hipMemsetAsync(ws + WS_CNT, 0, 256, stream);
  hipMemsetAsync(ws + WS_PERM, 0xFF, MT_MAX * BM * 4, stream);
  hipMemsetAsync(out, 0, (size_t)TOK * DD * 4, stream);  // split-K accumulates

  unsigned short* wb = (unsigned short*)(ws + WS_WB);
  const unsigned short* Xb = (const unsigned short*)(ws + WS_XB);
  const unsigned short* Hb = (const unsigned short*)(ws + WS_H);

  k_convert<<<2048, 256, 0, stream>>>(w1, wb, EE * FF * DD / 4);
  k_router<<<TOK / 4, 256, 0, stream>>>(x, gw, ws);
  k_finalize<<<1, 64, 0, stream>>>(ws, out);
  k_scatter<<<TOK / 256, 256, 0, stream>>>(ws);

  // GEMM1: [tokens x DD] @ w1^T -> gelu -> H   (grid 40 x 16, NS=32)
  k_gemm256<DD, FF, 1, true, true>
      <<<dim3(MT_MAX, FF / BN), NW, 0, stream>>>(Xb, wb, b1, ws, out);

  // convert w2 into the SAME buffer (w1b dead after GEMM1; stream-serial)
  k_convert<<<2048, 256, 0, stream>>>(w2, wb, EE * DD * FF / 4);

  // GEMM2: H @ w2^T -> scatter to out, split-K x2 (grid 40 x 8, NS=64)
  k_gemm256<FF, DD, 2, false, false>
      <<<dim3(MT_MAX, (DD / BN) * 2), NW, 0, stream>>>(Hb, wb, b2, ws, out);
}